// Round 9
// baseline (50.476 us; speedup 1.0000x reference)
//
#include <hip/hip_runtime.h>
#include <hip/hip_bf16.h>

// KoLeo loss, B=8192, D=256, TOPK=1.
// loss = mean_i( -log( ||x_i - x_{nn(i)}|| + 2*EPS ) ),  x = row-normalize(input)
// nn(i) = argmax_{j!=i} dot(x_i, x_j)  via bf16 MFMA Gram scan (selection only);
// the selected distance is recomputed exactly in fp32.
//
// argmax kernel: swapped-operand 32x32x16 MFMA, 64 owned cols/wave (2 B-sets,
// 128 regs), streamed rows via double-buffered XOR-swizzled LDS (0 conflicts).
// r8 lesson: phases were serializing (MfmaUtil == MFMA-floor/dur). This round:
// T15 deferred epilogue (2 static acc banks; sub-tile k's pack/max runs inside
// sub-tile k+1's ds/MFMA shadow), 2.5-VALU/elem packing (hq hoisted out,
// max3 pairs), TROWS=64 (8 barriers), stage-at-tile-top.

#define NB 8192
#define ND 256
#define ROWB 512          // bytes per row of bf16 x
#define EPSF 1e-8f
#define OWN 256           // owned cols per block (64 per wave)
#define CSL 512           // streamed rows per block slice
#define TROWS 64          // streamed rows per LDS tile (32 KB)
#define NT 8              // tiles per slice
#define TB 32768          // tile bytes

typedef __attribute__((ext_vector_type(8))) short short8;
typedef __attribute__((ext_vector_type(16))) float f32x16;
typedef unsigned long long ull;

__device__ __forceinline__ unsigned short f2bf(float f) {
    unsigned int u = __float_as_uint(f);
    unsigned int r = (u + 0x7FFFu + ((u >> 16) & 1u)) >> 16;   // RNE
    return (unsigned short)r;
}

__device__ __forceinline__ unsigned int fkey(float f) {
    unsigned int u = __float_as_uint(f);
    return (u & 0x80000000u) ? ~u : (u | 0x80000000u);
}

__device__ __forceinline__ void gload16(const void* g, void* l) {
    __builtin_amdgcn_global_load_lds(
        (const __attribute__((address_space(1))) unsigned int*)g,
        (__attribute__((address_space(3))) unsigned int*)l,
        16, 0, 0);
}

// ---------------- Phase A: row L2-normalize -> bf16 x, norms; zero `best` ----
__global__ __launch_bounds__(256) void koleo_normalize(const float* __restrict__ s,
                                                       unsigned int* __restrict__ xb_u32,
                                                       float* __restrict__ norms,
                                                       ull* __restrict__ best) {
    const int w = threadIdx.x >> 6, lane = threadIdx.x & 63;
    const int row = blockIdx.x * 4 + w;
    const float4 v = *(const float4*)(s + row * ND + lane * 4);
    float ss = v.x * v.x + v.y * v.y + v.z * v.z + v.w * v.w;
    #pragma unroll
    for (int m = 32; m; m >>= 1) ss += __shfl_xor(ss, m);
    const float nrm = sqrtf(ss);
    const float sc = 1.0f / (nrm + EPSF);
    uint2 pk;
    pk.x = (unsigned int)f2bf(v.x * sc) | ((unsigned int)f2bf(v.y * sc) << 16);
    pk.y = (unsigned int)f2bf(v.z * sc) | ((unsigned int)f2bf(v.w * sc) << 16);
    *(uint2*)(xb_u32 + (row * ND + lane * 4) / 2) = pk;
    if (lane == 0) { norms[row] = nrm; best[row] = 0ull; }
}

// ---------------- Phase B: swapped-operand MFMA argmax ------------------------
// grid (NB/OWN, NB/CSL) = (32, 16); block 256 = 4 waves; 2 blocks/CU.
__global__ __launch_bounds__(256, 2) void koleo_argmax(const short* __restrict__ x,
                                                       ull* __restrict__ best) {
    __shared__ __align__(16) char ldsc[2 * TB];   // 2 x 32 KB double buffer
    const int tid = threadIdx.x;
    const int lane = tid & 63;
    const int col = lane & 31;             // A row (streamed) / D col (owned)
    const int h = lane >> 5;               // k-half selector
    const int hq = h << 2;                 // D-row bit 2 (hoisted out of packing)
    const int i0 = blockIdx.x * OWN + (tid >> 6) * 64 + col;  // owned col, set 0
    const int i1 = i0 + 32;                                   // owned col, set 1
    const int sbase = blockIdx.y * CSL;
    const bool hasdiag = ((int)blockIdx.y == ((int)blockIdx.x >> 1));
    const int iloc0 = i0 - sbase, iloc1 = i1 - sbase;
    const char* xc = (const char*)x;

    // owned-col B fragments: 2 sets x 16 k-steps x 8 bf16 (128 regs)
    short8 bfrag[2][16];
    #pragma unroll
    for (int q = 0; q < 2; ++q) {
        const short* bp = x + (size_t)(i0 + 32 * q) * ND + h * 8;
        #pragma unroll
        for (int ks = 0; ks < 16; ++ks) bfrag[q][ks] = *(const short8*)(bp + ks * 16);
    }

    // staging: 8 x 16B chunks/thread/tile; LDS dest linear, source pre-swizzled
    int soff[8];
    #pragma unroll
    for (int ph = 0; ph < 8; ++ph) {
        const int idx = ph * 256 + tid;
        const int row = idx >> 5, c16 = idx & 31;
        soff[ph] = row * ROWB + ((c16 ^ (row & 31)) << 4);
    }
    const int ldsoff = tid << 4;
    // ds_read addressing: addr = abase ^ (ks<<5); buffer/subtile in offset imm
    const int abase = col * ROWB + ((h << 4) ^ (col << 4));

    float bd0 = -4.0f, bd1 = -4.0f;
    f32x16 accA0, accA1, accB0, accB1;     // two static banks (T15 defer)

    // prologue: stage tile 0 -> buf0
    {
        const char* gt = xc + (size_t)sbase * ROWB;
        #pragma unroll
        for (int ph = 0; ph < 8; ++ph)
            gload16(gt + soff[ph], ldsc + ph * 4096 + ldsoff);
    }
    __syncthreads();

    #define KL_STAGE(BUF, TILE) {                                                 \
        const char* gt = xc + (size_t)(sbase + (TILE) * TROWS) * ROWB;            \
        _Pragma("unroll")                                                         \
        for (int ph = 0; ph < 8; ++ph)                                            \
            gload16(gt + soff[ph], ldsc + (BUF) * TB + ph * 4096 + ldsoff); }

    #define KL_SUB(BUF, S, A0, A1) {                                              \
        _Pragma("unroll")                                                         \
        for (int z = 0; z < 16; ++z) { A0[z] = 0.f; A1[z] = 0.f; }                \
        _Pragma("unroll")                                                         \
        for (int ks = 0; ks < 16; ++ks) {                                         \
            const short8 a = *(const short8*)(ldsc + (BUF) * TB + (S) * 16384 +   \
                                              (abase ^ (ks << 5)));               \
            A0 = __builtin_amdgcn_mfma_f32_32x32x16_bf16(a, bfrag[0][ks], A0, 0, 0, 0); \
            A1 = __builtin_amdgcn_mfma_f32_32x32x16_bf16(a, bfrag[1][ks], A1, 0, 0, 0); } }

    // pack 9-bit local row id (sans hq bit) into low mantissa; fmax tracks both
    #define KL_EPI(VB, A0, A1) {                                                  \
        if (hasdiag) {                                                            \
            _Pragma("unroll")                                                     \
            for (int r = 0; r < 16; ++r) {                                        \
                const unsigned lr = (unsigned)((VB) | ((r & 3) + 8 * (r >> 2)));  \
                const float v0 = ((int)(lr | (unsigned)hq) == iloc0) ? -4.0f : A0[r]; \
                const float v1 = ((int)(lr | (unsigned)hq) == iloc1) ? -4.0f : A1[r]; \
                bd0 = fmaxf(bd0, __uint_as_float((__float_as_uint(v0) & 0xFFFFFE00u) | lr)); \
                bd1 = fmaxf(bd1, __uint_as_float((__float_as_uint(v1) & 0xFFFFFE00u) | lr)); } \
        } else {                                                                  \
            _Pragma("unroll")                                                     \
            for (int r = 0; r < 16; r += 2) {                                     \
                const unsigned lrA = (unsigned)((VB) | ((r & 3) + 8 * (r >> 2))); \
                const unsigned lrB = (unsigned)((VB) | (((r + 1) & 3) + 8 * ((r + 1) >> 2))); \
                const float p0 = __uint_as_float((__float_as_uint(A0[r]) & 0xFFFFFE00u) | lrA); \
                const float p1 = __uint_as_float((__float_as_uint(A0[r + 1]) & 0xFFFFFE00u) | lrB); \
                bd0 = fmaxf(fmaxf(p0, p1), bd0);                                  \
                const float q0 = __uint_as_float((__float_as_uint(A1[r]) & 0xFFFFFE00u) | lrA); \
                const float q1 = __uint_as_float((__float_as_uint(A1[r + 1]) & 0xFFFFFE00u) | lrB); \
                bd1 = fmaxf(fmaxf(q0, q1), bd1); } } }

    // ---- tile 0 (buf0) ----
    KL_STAGE(1, 1)
    KL_SUB(0, 0, accA0, accA1)
    KL_SUB(0, 1, accB0, accB1)
    KL_EPI(0, accA0, accA1)
    __syncthreads();
    // pending: (accB, tile0 s1)

    #pragma unroll 1
    for (int tt = 0; tt < 3; ++tt) {
        const int ta = 2 * tt + 1;          // odd tile -> buf1
        KL_STAGE(0, ta + 1)
        KL_SUB(1, 0, accA0, accA1)
        KL_EPI(((ta - 1) << 6) | 32, accB0, accB1)   // deferred prev s1
        KL_SUB(1, 1, accB0, accB1)
        KL_EPI(ta << 6, accA0, accA1)
        __syncthreads();
        const int tb = ta + 1;              // even tile -> buf0
        KL_STAGE(1, tb + 1)
        KL_SUB(0, 0, accA0, accA1)
        KL_EPI(((tb - 1) << 6) | 32, accB0, accB1)
        KL_SUB(0, 1, accB0, accB1)
        KL_EPI(tb << 6, accA0, accA1)
        __syncthreads();
    }
    // ---- tile 7 (buf1), no further staging ----
    KL_SUB(1, 0, accA0, accA1)
    KL_EPI((6 << 6) | 32, accB0, accB1)
    KL_SUB(1, 1, accB0, accB1)
    KL_EPI(7 << 6, accA0, accA1)
    KL_EPI((7 << 6) | 32, accB0, accB1)

    // restore hq bit, merge the two k-halves, then global merge
    bd0 = __uint_as_float(__float_as_uint(bd0) | (unsigned)hq);
    bd1 = __uint_as_float(__float_as_uint(bd1) | (unsigned)hq);
    {
        float o = __shfl_xor(bd0, 32); bd0 = fmaxf(bd0, o);
        o = __shfl_xor(bd1, 32); bd1 = fmaxf(bd1, o);
        if (lane < 32) {
            const int j0 = sbase + (int)(__float_as_uint(bd0) & 511u);
            const int j1 = sbase + (int)(__float_as_uint(bd1) & 511u);
            atomicMax(&best[i0], ((ull)fkey(bd0) << 32) | (unsigned int)j0);
            atomicMax(&best[i1], ((ull)fkey(bd1) << 32) | (unsigned int)j1);
        }
    }
}

// ---------------- Phase C: exact fp32 distances + partial loss sums -----------
// grid NB/16 = 512 blocks; 4 waves/block; each wave handles 4 rows.
__global__ __launch_bounds__(256) void koleo_dist(const float* __restrict__ s,
                                                  const float* __restrict__ norms,
                                                  const ull* __restrict__ best,
                                                  float* __restrict__ partial) {
    __shared__ float wsums[4];
    const int w = threadIdx.x >> 6, lane = threadIdx.x & 63;
    float acc = 0.f;
    #pragma unroll
    for (int t = 0; t < 4; ++t) {
        const int i = blockIdx.x * 16 + w * 4 + t;
        const int j = (int)(best[i] & 0xFFFFFFFFull);
        const float sci = 1.0f / (norms[i] + EPSF);
        const float scj = 1.0f / (norms[j] + EPSF);
        const float4 vi = *(const float4*)(s + i * ND + lane * 4);
        const float4 vj = *(const float4*)(s + j * ND + lane * 4);
        const float dx = vi.x * sci - vj.x * scj;
        const float dy = vi.y * sci - vj.y * scj;
        const float dz = vi.z * sci - vj.z * scj;
        const float dw = vi.w * sci - vj.w * scj;
        float d2 = dx * dx + dy * dy + dz * dz + dw * dw;
        #pragma unroll
        for (int mask = 32; mask; mask >>= 1) d2 += __shfl_xor(d2, mask);
        acc += -logf(sqrtf(d2) + EPSF + EPSF);
    }
    if (lane == 0) wsums[w] = acc;
    __syncthreads();
    if (threadIdx.x == 0) partial[blockIdx.x] = wsums[0] + wsums[1] + wsums[2] + wsums[3];
}

// ---------------- Phase D: final reduce (512 partials) ------------------------
__global__ __launch_bounds__(512) void koleo_final(const float* __restrict__ partial,
                                                   float* __restrict__ out) {
    __shared__ float w8[8];
    float v = partial[threadIdx.x];
    #pragma unroll
    for (int mask = 32; mask; mask >>= 1) v += __shfl_xor(v, mask);
    if ((threadIdx.x & 63) == 0) w8[threadIdx.x >> 6] = v;
    __syncthreads();
    if (threadIdx.x == 0) {
        float t = 0.f;
        #pragma unroll
        for (int k = 0; k < 8; ++k) t += w8[k];
        out[0] = t / (float)NB;
    }
}

extern "C" void kernel_launch(void* const* d_in, const int* in_sizes, int n_in,
                              void* d_out, int out_size, void* d_ws, size_t ws_size,
                              hipStream_t stream) {
    const float* s = (const float*)d_in[0];
    float* out = (float*)d_out;
    char* ws = (char*)d_ws;

    // ws layout
    unsigned int* xb = (unsigned int*)ws;                                   // 4 MiB bf16 x
    float* norms = (float*)(ws + 4 * 1024 * 1024);                          // 32 KiB
    ull* best = (ull*)(ws + 4 * 1024 * 1024 + 32 * 1024);                   // 64 KiB
    float* partial = (float*)(ws + 4 * 1024 * 1024 + 96 * 1024);            // 2 KiB

    koleo_normalize<<<NB / 4, 256, 0, stream>>>(s, xb, norms, best);
    koleo_argmax<<<dim3(NB / OWN, NB / CSL), 256, 0, stream>>>((const short*)xb, best);
    koleo_dist<<<NB / 16, 256, 0, stream>>>(s, norms, best, partial);
    koleo_final<<<1, 512, 0, stream>>>(partial, out);
}

// Round 10
// 44.278 us; speedup vs baseline: 1.1400x; 1.1400x over previous
//
#include <hip/hip_runtime.h>
#include <hip/hip_bf16.h>

// KoLeo loss, B=8192, D=256, TOPK=1.
// loss = mean_i( -log( ||x_i - x_{nn(i)}|| + 2*EPS ) ),  x = row-normalize(input)
// nn(i) = argmax_{j!=i} dot(x_i, x_j)  -- selection via INT8 MFMA Gram scan
// (q = round(360*x_hat), i32 dots, packed-index int max); the selected
// distance is recomputed exactly in fp32, so quantization only perturbs
// which near-tied neighbor is picked (est. loss bias ~3e-5 << 4.3e-3 thr).
//
// r7-r9 lesson: bf16 version stuck at ~36us regardless of schedule -- serial
// phase-sum at 2 waves/SIMD (reg-bound). i8 halves MFMA cyc, LDS bytes, and
// B-fragment registers (64 vs 128) -> ~127 regs -> 4 waves/SIMD, 4 blocks/CU.

#define NB 8192
#define ND 256
#define QROWB 256         // bytes per row of i8 q
#define EPSF 1e-8f
#define OWN 256           // owned cols per block (64 per wave)
#define CSL 256           // streamed rows per block slice
#define TROWS 64          // streamed rows per LDS tile (16 KB)
#define TB 16384          // tile bytes
#define QSCALE 360.0f

typedef __attribute__((ext_vector_type(4))) int i32x4;
typedef __attribute__((ext_vector_type(16))) int i32x16;
typedef unsigned long long ull;

__device__ __forceinline__ int imax(int a, int b) { return a > b ? a : b; }

__device__ __forceinline__ void gload16(const void* g, void* l) {
    __builtin_amdgcn_global_load_lds(
        (const __attribute__((address_space(1))) unsigned int*)g,
        (__attribute__((address_space(3))) unsigned int*)l,
        16, 0, 0);
}

// ---------------- Phase A: row L2-normalize -> i8 quant + norms; zero best ---
__global__ __launch_bounds__(256) void koleo_normalize(const float* __restrict__ s,
                                                       unsigned int* __restrict__ q32,
                                                       float* __restrict__ norms,
                                                       ull* __restrict__ best) {
    const int w = threadIdx.x >> 6, lane = threadIdx.x & 63;
    const int row = blockIdx.x * 4 + w;
    const float4 v = *(const float4*)(s + row * ND + lane * 4);
    float ss = v.x * v.x + v.y * v.y + v.z * v.z + v.w * v.w;
    #pragma unroll
    for (int m = 32; m; m >>= 1) ss += __shfl_xor(ss, m);
    const float nrm = sqrtf(ss);
    const float qs = QSCALE / (nrm + EPSF);
    const int a0 = __float2int_rn(fmaxf(-127.f, fminf(127.f, v.x * qs)));
    const int a1 = __float2int_rn(fmaxf(-127.f, fminf(127.f, v.y * qs)));
    const int a2 = __float2int_rn(fmaxf(-127.f, fminf(127.f, v.z * qs)));
    const int a3 = __float2int_rn(fmaxf(-127.f, fminf(127.f, v.w * qs)));
    const unsigned pk = (unsigned)(a0 & 255) | ((unsigned)(a1 & 255) << 8) |
                        ((unsigned)(a2 & 255) << 16) | ((unsigned)(a3 & 255) << 24);
    q32[row * (QROWB / 4) + lane] = pk;
    if (lane == 0) { norms[row] = nrm; best[row] = 0ull; }
}

// ---------------- Phase B: swapped-operand i8 MFMA argmax ---------------------
// grid (NB/OWN, NB/CSL) = (32, 32) = 1024 blocks; 4 waves/block; 4 blocks/CU.
// Wave holds 64 owned cols as two B-sets (64 regs); streamed rows through
// double-buffered XOR-swizzled LDS (slot16 ^= row&15: 8 lanes/bank-cluster =
// the b128 minimum). D layout: col=lane&31, row=(r&3)+8*(r>>2)+4*(lane>>5).
__global__ __launch_bounds__(256, 4) void koleo_argmax(const char* __restrict__ q8,
                                                       ull* __restrict__ best) {
    __shared__ __align__(16) char ldsc[2 * TB];   // 2 x 16 KB double buffer
    const int tid = threadIdx.x;
    const int lane = tid & 63;
    const int col = lane & 31;             // A row (streamed) / D col (owned)
    const int h = lane >> 5;               // k-half selector
    const int i0 = blockIdx.x * OWN + (tid >> 6) * 64 + col;  // owned col, set 0
    const int i1 = i0 + 32;                                   // owned col, set 1
    const int sbase = blockIdx.y * CSL;
    const bool hasdiag = (blockIdx.x == blockIdx.y);
    const int iloc0 = i0 - sbase, iloc1 = i1 - sbase;

    // owned-col B fragments: 2 sets x 8 k-steps x 16 i8 (64 regs total)
    i32x4 bfr0[8], bfr1[8];
    {
        const char* bp0 = q8 + (size_t)i0 * QROWB + h * 16;
        const char* bp1 = q8 + (size_t)i1 * QROWB + h * 16;
        #pragma unroll
        for (int ks = 0; ks < 8; ++ks) {
            bfr0[ks] = *(const i32x4*)(bp0 + ks * 32);
            bfr1[ks] = *(const i32x4*)(bp1 + ks * 32);
        }
    }

    // staging: 4 x 16B chunks/thread/tile; LDS dest linear, source pre-swizzled
    // with slot16 ^= row&15 (involution within each 256 B row)
    int soff[4];
    #pragma unroll
    for (int ph = 0; ph < 4; ++ph) {
        const int idx = ph * 256 + tid;
        const int row = idx >> 4, c16 = idx & 15;
        soff[ph] = row * QROWB + ((c16 ^ (row & 15)) << 4);
    }
    const int ldsoff = tid << 4;
    // ds_read: row = s*32+col, slot = (2ks+h) ^ (col&15); buf/s in offset imm
    const int abase = col * QROWB + ((h << 4) ^ ((col & 15) << 4));

    int bd0 = (int)0x80000000, bd1 = (int)0x80000000;

    #define KL_STAGE(BUF, TILE) {                                                 \
        const char* gt = q8 + (size_t)(sbase + (TILE) * TROWS) * QROWB;           \
        _Pragma("unroll")                                                         \
        for (int ph = 0; ph < 4; ++ph)                                            \
            gload16(gt + soff[ph], ldsc + (BUF) * TB + ph * 4096 + ldsoff); }

    // packed key = dot*256 + lr  (|dot| <= 129600 < 2^23 -> mad_i24; lr < 256)
    #define KL_COMP(BUF, TILE) {                                                  \
        _Pragma("unroll")                                                         \
        for (int s = 0; s < 2; ++s) {                                             \
            i32x16 a0, a1;                                                        \
            _Pragma("unroll")                                                     \
            for (int z = 0; z < 16; ++z) { a0[z] = 0; a1[z] = 0; }                \
            _Pragma("unroll")                                                     \
            for (int ks = 0; ks < 8; ++ks) {                                      \
                const i32x4 av = *(const i32x4*)(ldsc + (BUF) * TB + s * 8192 +   \
                                                 (abase ^ (ks << 5)));            \
                a0 = __builtin_amdgcn_mfma_i32_32x32x32_i8(av, bfr0[ks], a0, 0, 0, 0); \
                a1 = __builtin_amdgcn_mfma_i32_32x32x32_i8(av, bfr1[ks], a1, 0, 0, 0); \
            }                                                                     \
            const int vb = ((TILE) * 64) | (s * 32) | (h << 2);                   \
            if (hasdiag) {                                                        \
                _Pragma("unroll")                                                 \
                for (int r = 0; r < 16; ++r) {                                    \
                    const int lr = vb | ((r & 3) + 8 * (r >> 2));                 \
                    int k0 = a0[r] * 256 + lr;                                    \
                    int k1 = a1[r] * 256 + lr;                                    \
                    if (lr == iloc0) k0 = (int)0x80000000;                        \
                    if (lr == iloc1) k1 = (int)0x80000000;                        \
                    bd0 = imax(bd0, k0); bd1 = imax(bd1, k1);                     \
                }                                                                 \
            } else {                                                              \
                _Pragma("unroll")                                                 \
                for (int r = 0; r < 16; ++r) {                                    \
                    const int lr = vb | ((r & 3) + 8 * (r >> 2));                 \
                    bd0 = imax(bd0, a0[r] * 256 + lr);                            \
                    bd1 = imax(bd1, a1[r] * 256 + lr);                            \
                }                                                                 \
            }                                                                     \
        } }

    // 4 tiles, classic 2-phase double buffer (stage issued at phase top)
    KL_STAGE(0, 0)
    __syncthreads();
    KL_STAGE(1, 1) KL_COMP(0, 0)
    __syncthreads();
    KL_STAGE(0, 2) KL_COMP(1, 1)
    __syncthreads();
    KL_STAGE(1, 3) KL_COMP(0, 2)
    __syncthreads();
    KL_COMP(1, 3)

    // merge the two k-halves (disjoint row sets), then global merge
    {
        const int o0 = __shfl_xor(bd0, 32); bd0 = imax(bd0, o0);
        const int o1 = __shfl_xor(bd1, 32); bd1 = imax(bd1, o1);
        if (lane < 32) {
            const unsigned uk0 = (unsigned)bd0 ^ 0x80000000u;
            const unsigned uk1 = (unsigned)bd1 ^ 0x80000000u;
            const unsigned j0 = (unsigned)(sbase + (bd0 & 255));
            const unsigned j1 = (unsigned)(sbase + (bd1 & 255));
            atomicMax(&best[i0], ((ull)uk0 << 32) | j0);
            atomicMax(&best[i1], ((ull)uk1 << 32) | j1);
        }
    }
}

// ---------------- Phase C: exact fp32 distances + partial loss sums -----------
// grid NB/16 = 512 blocks; 4 waves/block; each wave handles 4 rows.
__global__ __launch_bounds__(256) void koleo_dist(const float* __restrict__ s,
                                                  const float* __restrict__ norms,
                                                  const ull* __restrict__ best,
                                                  float* __restrict__ partial) {
    __shared__ float wsums[4];
    const int w = threadIdx.x >> 6, lane = threadIdx.x & 63;
    float acc = 0.f;
    #pragma unroll
    for (int t = 0; t < 4; ++t) {
        const int i = blockIdx.x * 16 + w * 4 + t;
        const int j = (int)(best[i] & 0xFFFFFFFFull);
        const float sci = 1.0f / (norms[i] + EPSF);
        const float scj = 1.0f / (norms[j] + EPSF);
        const float4 vi = *(const float4*)(s + i * ND + lane * 4);
        const float4 vj = *(const float4*)(s + j * ND + lane * 4);
        const float dx = vi.x * sci - vj.x * scj;
        const float dy = vi.y * sci - vj.y * scj;
        const float dz = vi.z * sci - vj.z * scj;
        const float dw = vi.w * sci - vj.w * scj;
        float d2 = dx * dx + dy * dy + dz * dz + dw * dw;
        #pragma unroll
        for (int mask = 32; mask; mask >>= 1) d2 += __shfl_xor(d2, mask);
        acc += -logf(sqrtf(d2) + EPSF + EPSF);
    }
    if (lane == 0) wsums[w] = acc;
    __syncthreads();
    if (threadIdx.x == 0) partial[blockIdx.x] = wsums[0] + wsums[1] + wsums[2] + wsums[3];
}

// ---------------- Phase D: final reduce (512 partials) ------------------------
__global__ __launch_bounds__(512) void koleo_final(const float* __restrict__ partial,
                                                   float* __restrict__ out) {
    __shared__ float w8[8];
    float v = partial[threadIdx.x];
    #pragma unroll
    for (int mask = 32; mask; mask >>= 1) v += __shfl_xor(v, mask);
    if ((threadIdx.x & 63) == 0) w8[threadIdx.x >> 6] = v;
    __syncthreads();
    if (threadIdx.x == 0) {
        float t = 0.f;
        #pragma unroll
        for (int k = 0; k < 8; ++k) t += w8[k];
        out[0] = t / (float)NB;
    }
}

extern "C" void kernel_launch(void* const* d_in, const int* in_sizes, int n_in,
                              void* d_out, int out_size, void* d_ws, size_t ws_size,
                              hipStream_t stream) {
    const float* s = (const float*)d_in[0];
    float* out = (float*)d_out;
    char* ws = (char*)d_ws;

    // ws layout
    char* q8 = ws;                                                          // 2 MiB i8 q
    float* norms = (float*)(ws + 2 * 1024 * 1024);                          // 32 KiB
    ull* best = (ull*)(ws + 2 * 1024 * 1024 + 32 * 1024);                   // 64 KiB
    float* partial = (float*)(ws + 2 * 1024 * 1024 + 96 * 1024);            // 2 KiB

    koleo_normalize<<<NB / 4, 256, 0, stream>>>(s, (unsigned int*)q8, norms, best);
    koleo_argmax<<<dim3(NB / OWN, NB / CSL), 256, 0, stream>>>(q8, best);
    koleo_dist<<<NB / 16, 256, 0, stream>>>(s, norms, best, partial);
    koleo_final<<<1, 512, 0, stream>>>(partial, out);
}